// Round 1
// baseline (269.642 us; speedup 1.0000x reference)
//
#include <hip/hip_runtime.h>

// PEG_Shift: depthwise 3x3 conv (stride 1, pad 1, groups=C) with
//   - weights rounded to signed powers of two (5-bit shift, clamp |w| to [2^-14, 1])
//   - activations/bias in 16-bit fixed point (floor(x*2^16)*2^-16, clip [-32768, 32767])
// x: (32, 384, 56, 56) f32, weight: (384,1,3,3) f32, bias: (384,) f32 -> out f32 same shape as x.
//
// Memory-bound: ~308 MB HBM traffic -> ~50 us floor at 6.3 TB/s.
// One block per (n,c) plane; plane staged+quantized in LDS (12.25 KB), 4 outputs/thread/iter.

#define DW_C   384
#define DW_H   56
#define DW_W   56
#define DW_HW  (DW_H * DW_W)   // 3136
#define DW_HW4 (DW_HW / 4)     // 784
#define DW_W4  (DW_W / 4)      // 14

__device__ __forceinline__ float qfix(float v) {
    // floor(v / 2^-16) * 2^-16, clipped to [-2^15, 2^15 - 1] — exact in fp32
    v = floorf(v * 65536.0f) * (1.0f / 65536.0f);
    return fminf(fmaxf(v, -32768.0f), 32767.0f);
}

__global__ __launch_bounds__(256) void peg_shift_dwconv(
    const float* __restrict__ x, const float* __restrict__ wgt,
    const float* __restrict__ bias, float* __restrict__ out)
{
    __shared__ float s[DW_HW];

    const int plane = blockIdx.x;        // n*C + c
    const int c = plane % DW_C;
    const float* xp = x + (size_t)plane * DW_HW;
    float* op = out + (size_t)plane * DW_HW;

    // ---- stage plane into LDS, quantizing activations on the way in ----
    const float4* xp4 = (const float4*)xp;
    float4* s4 = (float4*)s;
    for (int i = threadIdx.x; i < DW_HW4; i += 256) {
        float4 v = xp4[i];
        v.x = qfix(v.x); v.y = qfix(v.y); v.z = qfix(v.z); v.w = qfix(v.w);
        s4[i] = v;
    }

    // ---- quantize the 9 per-channel weights (power of two) + bias (fixed point) ----
    // uniform per block -> scalar broadcast loads
    float wq[9];
#pragma unroll
    for (int k = 0; k < 9; ++k) {
        float wv = wgt[c * 9 + k];
        float aw = fabsf(wv);
        float cw = fminf(fmaxf(aw, 6.103515625e-05f /*2^-14*/), 1.0f);
        float q  = exp2f(rintf(log2f(cw)));   // rint = round-half-even, matches jnp.round
        wq[k] = (wv > 0.0f) ? q : ((wv < 0.0f) ? -q : 0.0f);
    }
    float bq = qfix(bias[c]);

    __syncthreads();

    // ---- compute: 4 contiguous outputs per thread per iteration ----
    for (int iv = threadIdx.x; iv < DW_HW4; iv += 256) {
        int h  = iv / DW_W4;
        int w0 = (iv - h * DW_W4) * 4;     // 0..52, multiple of 4 (float4-aligned)
        float a0 = bq, a1 = bq, a2 = bq, a3 = bq;
#pragma unroll
        for (int dh = 0; dh < 3; ++dh) {
            int hh = h + dh - 1;
            if (hh < 0 || hh >= DW_H) continue;   // zero-pad rows
            const float* row = s + hh * DW_W;
            float4 m = *(const float4*)(row + w0);            // ds_read_b128, aligned
            float left  = (w0 > 0)        ? row[w0 - 1] : 0.0f;
            float right = (w0 < DW_W - 4) ? row[w0 + 4] : 0.0f;
            float wl = wq[dh * 3 + 0], wm = wq[dh * 3 + 1], wr = wq[dh * 3 + 2];
            a0 += left * wl + m.x * wm + m.y * wr;
            a1 += m.x  * wl + m.y * wm + m.z * wr;
            a2 += m.y  * wl + m.z * wm + m.w * wr;
            a3 += m.z  * wl + m.w * wm + right * wr;
        }
        float4 o; o.x = a0; o.y = a1; o.z = a2; o.w = a3;
        ((float4*)op)[iv] = o;
    }
}

extern "C" void kernel_launch(void* const* d_in, const int* in_sizes, int n_in,
                              void* d_out, int out_size, void* d_ws, size_t ws_size,
                              hipStream_t stream) {
    const float* x = (const float*)d_in[0];
    const float* w = (const float*)d_in[1];
    const float* b = (const float*)d_in[2];
    float* out = (float*)d_out;

    int planes = in_sizes[0] / DW_HW;   // 32 * 384 = 12288
    peg_shift_dwconv<<<planes, 256, 0, stream>>>(x, w, b, out);
}